// Round 4
// baseline (734.919 us; speedup 1.0000x reference)
//
#include <hip/hip_runtime.h>

#define N_ENT   50000
#define CH      128
#define N_EDGES 1600000
#define N_RELM1 10
#define NB      391           // ceil(N_ENT / 128) buckets of 128 heads
#define BCAP    4608          // bucket capacity (verified r8: max bucket fits)
#define PART_BLOCKS 800
#define CHUNK   (N_EDGES / PART_BLOCKS)   // 2000 exactly
#define NRG     (N_ENT / 8)   // 6250 rowgroups of 8 heads
#define NKEY    2048          // (rg:4)(g:4)(r:3) sort bins per bucket
#define EPS_N   1e-12f

__device__ __forceinline__ unsigned int f2bf_bits(float f) {
    unsigned int x = __float_as_uint(f);
    return (x + 0x7FFFu + ((x >> 16) & 1u)) >> 16;   // RNE; values are finite
}

// Per block: ONE pass over its 2000 edges, stage entry+bucket in LDS,
// histogram, scan, LDS bin-scatter, coalesced write-out. Fused bf16 cvt.
// entry = tail(16) | rel(4)<<16 | hlow(7)<<20
__global__ __launch_bounds__(256) void gc_part_kernel(const int* __restrict__ head,
                                                      const int* __restrict__ tail,
                                                      const int* __restrict__ etyp,
                                                      int* __restrict__ barr,
                                                      int* __restrict__ pack,
                                                      const float* __restrict__ ent,
                                                      unsigned int* __restrict__ emb) {
    __shared__ int hist[512];                // NB bins padded
    __shared__ int boff_s[512];
    __shared__ int fctr[512];
    __shared__ int psum[256];
    __shared__ int stageE[CHUNK];            // raw entries (8 KB)
    __shared__ unsigned short stageB[CHUNK]; // bucket ids (4 KB)
    __shared__ int stage2[CHUNK];            // binned entries (8 KB)
    int tid = threadIdx.x, blk = blockIdx.x;
    for (int i = tid; i < 512; i += 256) { hist[i] = 0; fctr[i] = 0; }
    __syncthreads();
    int lo = blk * CHUNK;
    for (int i = tid; i < CHUNK; i += 256) {
        int e = lo + i;
        int h = head[e];
        int b = h >> 7;
        stageE[i] = (tail[e] & 0xFFFF) | ((etyp[e] - 1) << 16) | ((h & 127) << 20);
        stageB[i] = (unsigned short)b;
        atomicAdd(&hist[b], 1);
    }
    __syncthreads();
    // exclusive scan of 512 bins: 2 bins/thread + 256-ladder
    int a0 = hist[2 * tid], a1 = hist[2 * tid + 1];
    int s2 = a0 + a1;
    psum[tid] = s2;
    __syncthreads();
    for (int d = 1; d < 256; d <<= 1) {
        int t = (tid >= d) ? psum[tid - d] : 0;
        __syncthreads();
        psum[tid] += t;
        __syncthreads();
    }
    int excl = psum[tid] - s2;
    boff_s[2 * tid] = excl;
    boff_s[2 * tid + 1] = excl + a0;
    __syncthreads();
    for (int i = tid; i < CHUNK; i += 256) {
        int b = stageB[i];
        int pos = boff_s[b] + atomicAdd(&fctr[b], 1);
        stage2[pos] = stageE[i];
    }
    __syncthreads();
    for (int i = tid; i < CHUNK; i += 256) barr[lo + i] = stage2[i];
    for (int i = tid; i < NB; i += 256)
        pack[blk * NB + i] = (boff_s[i] << 8) | fctr[i];
    // fused cvt (independent streaming work)
    for (int i = blk * 256 + tid; i < N_ENT * (CH / 2); i += PART_BLOCKS * 256) {
        float2 v = *(const float2*)(ent + 2 * (size_t)i);
        emb[i] = f2bf_bits(v.x) | (f2bf_bits(v.y) << 16);
    }
}

// per bucket: gather the 800 part-block windows to LDS, then sort entries by
// key = (rowgroup:4 | tailgroup:4 | row:3). Emits per-row degree, per-rowgroup
// csr start, and csr entries (tail|rel|r) ordered by tail-group so the hop
// kernel's chip-wide gather window is ~1-2 MB at any instant (L2-resident).
__global__ __launch_bounds__(1024) void gc_place_kernel(const int* __restrict__ barr,
                                                        const int* __restrict__ pack,
                                                        int* __restrict__ deg_arr,
                                                        int* __restrict__ rg_off,
                                                        int* __restrict__ csr) {
    __shared__ int ent_s[BCAP];
    __shared__ int psum[1024];
    __shared__ int kcnt[NKEY];
    __shared__ int kctr[NKEY];
    __shared__ int kbase[NKEY];
    int b = blockIdx.x, tid = threadIdx.x;
    kcnt[tid] = 0; kcnt[tid + 1024] = 0;
    kctr[tid] = 0; kctr[tid + 1024] = 0;
    int c = 0, o = 0;
    if (tid < PART_BLOCKS) {
        int pk = pack[tid * NB + b];
        c = pk & 255;
        o = pk >> 8;
    }
    psum[tid] = c;
    __syncthreads();
    for (int d = 1; d < 1024; d <<= 1) {
        int t = (tid >= d) ? psum[tid - d] : 0;
        __syncthreads();
        psum[tid] += t;
        __syncthreads();
    }
    int my_off = psum[tid] - c;
    int n = psum[1023];
    const int* src = barr + tid * CHUNK + o;
    for (int k = 0; k < c; ++k) ent_s[my_off + k] = src[k];
    __syncthreads();
    // histogram over 2048 keys
    for (int i = tid; i < n; i += 1024) {
        int e = ent_s[i];
        int hl = (e >> 20) & 127;
        int key = ((hl >> 3) << 7) | (((e & 0xFFFF) >> 12) << 3) | (hl & 7);
        atomicAdd(&kcnt[key], 1);
    }
    __syncthreads();
    // per-row degree (reads raw kcnt; kcnt is not modified below)
    if (tid < 128) {
        int rgl = tid >> 3, r = tid & 7;
        int d = 0;
        #pragma unroll
        for (int g = 0; g < 16; ++g) d += kcnt[(rgl << 7) | (g << 3) | r];
        int h = (b << 7) + tid;
        if (h < N_ENT) deg_arr[h] = d;
    }
    // exclusive scan of 2048 bins: 2 bins/thread + 1024-ladder
    int a0 = kcnt[2 * tid], a1 = kcnt[2 * tid + 1];
    int s2 = a0 + a1;
    psum[tid] = s2;
    __syncthreads();
    for (int d = 1; d < 1024; d <<= 1) {
        int t = (tid >= d) ? psum[tid - d] : 0;
        __syncthreads();
        psum[tid] += t;
        __syncthreads();
    }
    int excl = psum[tid] - s2;
    kbase[2 * tid] = excl;
    kbase[2 * tid + 1] = excl + a0;
    __syncthreads();
    int lo = b * BCAP;
    if (tid < 16) {
        int grg = (b << 4) + tid;
        if (grg < NRG) rg_off[grg] = lo + kbase[tid << 7];
    }
    for (int i = tid; i < n; i += 1024) {
        int e = ent_s[i];
        int hl = (e >> 20) & 127;
        int key = ((hl >> 3) << 7) | (((e & 0xFFFF) >> 12) << 3) | (hl & 7);
        int pos = lo + kbase[key] + atomicAdd(&kctr[key], 1);
        csr[pos] = (e & 0xFFFFF) | ((hl & 7) << 20);   // tail | rel<<16 | r<<20
    }
}

// one wave64 per 8 rows (rowgroup). All 6250 waves co-resident; each sweeps
// its tail-group-sorted list monotonically (L2-sized chip-wide window).
// Metadata path is COMPILER-VISIBLE: wave-uniform broadcast int4 loads +
// readfirstlane into SGPRs (uniform switch, SALU gather addressing) — no
// inline-asm SMEM, so all vmcnt/lgkmcnt waits are counted & correct.
// Phase-split ping-pong pipeline: meta 1 chunk ahead, values 1 chunk ahead,
// weights reissued right after ACC; no in-flight register is ever copied.
__global__ __launch_bounds__(256, 7) void gc_hop_kernel(
        const unsigned int* __restrict__ src,     // bf16x2 per uint
        const int* __restrict__ deg_arr,
        const int* __restrict__ rg_off,
        const int* __restrict__ csr,
        const float* __restrict__ wt,
        unsigned int* __restrict__ dst,
        float* __restrict__ res,
        const float* __restrict__ ent,
        const unsigned int* __restrict__ yprev,
        int mode) {
    __shared__ float wt_s[16 * CH];   // padded to 16 rels: over-issued reads stay in-bounds
    for (int i = threadIdx.x; i < N_RELM1 * CH; i += 256) wt_s[i] = wt[i];
    __syncthreads();

    int wave = threadIdx.x >> 6, lane = threadIdx.x & 63;
    int rg = __builtin_amdgcn_readfirstlane(blockIdx.x * 4 + wave);
    if (rg >= NRG) return;    // no barriers below

    const int4* dp = (const int4*)deg_arr + rg * 2;   // 32B aligned
    int4 dd0 = dp[0], dd1 = dp[1];
    int odv = rg_off[rg];
    int D0 = __builtin_amdgcn_readfirstlane(dd0.x);
    int D1 = __builtin_amdgcn_readfirstlane(dd0.y);
    int D2 = __builtin_amdgcn_readfirstlane(dd0.z);
    int D3 = __builtin_amdgcn_readfirstlane(dd0.w);
    int D4 = __builtin_amdgcn_readfirstlane(dd1.x);
    int D5 = __builtin_amdgcn_readfirstlane(dd1.y);
    int D6 = __builtin_amdgcn_readfirstlane(dd1.z);
    int D7 = __builtin_amdgcn_readfirstlane(dd1.w);
    int seg = __builtin_amdgcn_readfirstlane(odv);
    int nedges = D0 + D1 + D2 + D3 + D4 + D5 + D6 + D7;

    float ax0 = 0.f, ay0 = 0.f, ax1 = 0.f, ay1 = 0.f;
    float ax2 = 0.f, ay2 = 0.f, ax3 = 0.f, ay3 = 0.f;
    float ax4 = 0.f, ay4 = 0.f, ax5 = 0.f, ay5 = 0.f;
    float ax6 = 0.f, ay6 = 0.f, ax7 = 0.f, ay7 = 0.f;

    const unsigned* srcl = src + lane;                  // lane offset folded once
    const float2*   wl   = (const float2*)wt_s + lane;  // wt_s[rel*CH + 2*lane]

#define RFL8(ma, mb, p) \
    p##0 = __builtin_amdgcn_readfirstlane((ma).x); \
    p##1 = __builtin_amdgcn_readfirstlane((ma).y); \
    p##2 = __builtin_amdgcn_readfirstlane((ma).z); \
    p##3 = __builtin_amdgcn_readfirstlane((ma).w); \
    p##4 = __builtin_amdgcn_readfirstlane((mb).x); \
    p##5 = __builtin_amdgcn_readfirstlane((mb).y); \
    p##6 = __builtin_amdgcn_readfirstlane((mb).z); \
    p##7 = __builtin_amdgcn_readfirstlane((mb).w);

#define ISSUE_VAL(p, vv) \
    vv[0] = srcl[(unsigned)(p##0 & 0xFFFF) * 64u]; \
    vv[1] = srcl[(unsigned)(p##1 & 0xFFFF) * 64u]; \
    vv[2] = srcl[(unsigned)(p##2 & 0xFFFF) * 64u]; \
    vv[3] = srcl[(unsigned)(p##3 & 0xFFFF) * 64u]; \
    vv[4] = srcl[(unsigned)(p##4 & 0xFFFF) * 64u]; \
    vv[5] = srcl[(unsigned)(p##5 & 0xFFFF) * 64u]; \
    vv[6] = srcl[(unsigned)(p##6 & 0xFFFF) * 64u]; \
    vv[7] = srcl[(unsigned)(p##7 & 0xFFFF) * 64u];

#define ISSUE_WT(p) \
    w[0] = wl[((p##0 >> 16) & 15) * 64]; \
    w[1] = wl[((p##1 >> 16) & 15) * 64]; \
    w[2] = wl[((p##2 >> 16) & 15) * 64]; \
    w[3] = wl[((p##3 >> 16) & 15) * 64]; \
    w[4] = wl[((p##4 >> 16) & 15) * 64]; \
    w[5] = wl[((p##5 >> 16) & 15) * 64]; \
    w[6] = wl[((p##6 >> 16) & 15) * 64]; \
    w[7] = wl[((p##7 >> 16) & 15) * 64];

#define ACCONE(e_, vv, ww) { \
        float vx = __uint_as_float((vv) << 16); \
        float vy = __uint_as_float((vv) & 0xFFFF0000u); \
        switch ((e_) >> 20) { \
        case 0: ax0 = fmaf(vx, (ww).x, ax0); ay0 = fmaf(vy, (ww).y, ay0); break; \
        case 1: ax1 = fmaf(vx, (ww).x, ax1); ay1 = fmaf(vy, (ww).y, ay1); break; \
        case 2: ax2 = fmaf(vx, (ww).x, ax2); ay2 = fmaf(vy, (ww).y, ay2); break; \
        case 3: ax3 = fmaf(vx, (ww).x, ax3); ay3 = fmaf(vy, (ww).y, ay3); break; \
        case 4: ax4 = fmaf(vx, (ww).x, ax4); ay4 = fmaf(vy, (ww).y, ay4); break; \
        case 5: ax5 = fmaf(vx, (ww).x, ax5); ay5 = fmaf(vy, (ww).y, ay5); break; \
        case 6: ax6 = fmaf(vx, (ww).x, ax6); ay6 = fmaf(vy, (ww).y, ay6); break; \
        default: ax7 = fmaf(vx, (ww).x, ax7); ay7 = fmaf(vy, (ww).y, ay7); break; \
        } }

#define ACC_FULL(p, vv) \
    ACCONE(p##0, vv[0], w[0]) ACCONE(p##1, vv[1], w[1]) \
    ACCONE(p##2, vv[2], w[2]) ACCONE(p##3, vv[3], w[3]) \
    ACCONE(p##4, vv[4], w[4]) ACCONE(p##5, vv[5], w[5]) \
    ACCONE(p##6, vv[6], w[6]) ACCONE(p##7, vv[7], w[7])

#define ACC_LEAD(p, vv, ld) \
    if ((ld) <= 0) ACCONE(p##0, vv[0], w[0]) if ((ld) <= 1) ACCONE(p##1, vv[1], w[1]) \
    if ((ld) <= 2) ACCONE(p##2, vv[2], w[2]) if ((ld) <= 3) ACCONE(p##3, vv[3], w[3]) \
    if ((ld) <= 4) ACCONE(p##4, vv[4], w[4]) if ((ld) <= 5) ACCONE(p##5, vv[5], w[5]) \
    if ((ld) <= 6) ACCONE(p##6, vv[6], w[6]) ACCONE(p##7, vv[7], w[7])

#define ACC_TAIL(p, vv, n) \
    if ((n) > 0) ACCONE(p##0, vv[0], w[0]) if ((n) > 1) ACCONE(p##1, vv[1], w[1]) \
    if ((n) > 2) ACCONE(p##2, vv[2], w[2]) if ((n) > 3) ACCONE(p##3, vv[3], w[3]) \
    if ((n) > 4) ACCONE(p##4, vv[4], w[4]) if ((n) > 5) ACCONE(p##5, vv[5], w[5]) \
    if ((n) > 6) ACCONE(p##6, vv[6], w[6]) if ((n) > 7) ACCONE(p##7, vv[7], w[7])

#define ACC_RANGE(p, vv, ld, hi) \
    if ((ld) <= 0 && (hi) > 0) ACCONE(p##0, vv[0], w[0]) \
    if ((ld) <= 1 && (hi) > 1) ACCONE(p##1, vv[1], w[1]) \
    if ((ld) <= 2 && (hi) > 2) ACCONE(p##2, vv[2], w[2]) \
    if ((ld) <= 3 && (hi) > 3) ACCONE(p##3, vv[3], w[3]) \
    if ((ld) <= 4 && (hi) > 4) ACCONE(p##4, vv[4], w[4]) \
    if ((ld) <= 5 && (hi) > 5) ACCONE(p##5, vv[5], w[5]) \
    if ((ld) <= 6 && (hi) > 6) ACCONE(p##6, vv[6], w[6]) \
    if ((ld) <= 7 && (hi) > 7) ACCONE(p##7, vv[7], w[7])

#define COPY_EF() \
    e0 = f0; e1 = f1; e2 = f2; e3 = f3; e4 = f4; e5 = f5; e6 = f6; e7 = f7;

    if (nedges > 0) {
        // align the metadata stream to 32B; mask the leading (seg&7) entries
        int seg0 = seg & ~7;
        int lead = seg & 7;
        int total = lead + nedges;
        int nch = (total + 7) >> 3;
        int rem = total - ((nch - 1) << 3);       // 1..8
        const int4* mp = (const int4*)(csr + seg0);

        unsigned v0[8], v1[8];
        float2 w[8];
        int e0, e1, e2, e3, e4, e5, e6, e7;
        int f0, f1, f2, f3, f4, f5, f6, f7;

        int4 mA0 = mp[0], mA1 = mp[1];            // meta chunk0
        RFL8(mA0, mA1, e);
        ISSUE_VAL(e, v0);
        ISSUE_WT(e);
        if (nch == 1) {
            ACC_RANGE(e, v0, lead, total);
        } else {
            int4 mB0 = mp[2], mB1 = mp[3];        // meta chunk1 (in flight)
            int c = 1;
            for (;;) {
                // A-phase: chunk c -> values v1
                RFL8(mB0, mB1, f);                // waits mB (issued last phase)
                mA0 = mp[2 * c + 2]; mA1 = mp[2 * c + 3];   // meta c+1 (mA dead)
                ISSUE_VAL(f, v1);
                if (c == 1) { ACC_LEAD(e, v0, lead) }
                else        { ACC_FULL(e, v0) }
                ISSUE_WT(f);                      // w dead after ACC -> reuse
                COPY_EF();
                if (c == nch - 1) { ACC_TAIL(e, v1, rem) break; }
                ++c;
                // B-phase: chunk c -> values v0
                RFL8(mA0, mA1, f);
                mB0 = mp[2 * c + 2]; mB1 = mp[2 * c + 3];
                ISSUE_VAL(f, v0);
                ACC_FULL(e, v1)
                ISSUE_WT(f);
                COPY_EF();
                if (c == nch - 1) { ACC_TAIL(e, v0, rem) break; }
                ++c;
            }
        }
    }
#undef RFL8
#undef ISSUE_VAL
#undef ISSUE_WT
#undef ACCONE
#undef ACC_FULL
#undef ACC_LEAD
#undef ACC_TAIL
#undef ACC_RANGE
#undef COPY_EF

#define ROWOUT(r, axr, ayr, Dr) { \
        int row = (rg << 3) + r; \
        float invd = 1.0f / fmaxf((float)Dr, 1.0f); \
        float x0 = axr * invd, x1 = ayr * invd; \
        float s = x0 * x0 + x1 * x1; \
        _Pragma("unroll") \
        for (int o = 32; o; o >>= 1) s += __shfl_xor(s, o, 64); \
        float inv = 1.0f / fmaxf(sqrtf(s), EPS_N); \
        float y0 = x0 * inv, y1v = x1 * inv; \
        if (mode == 0) { \
            dst[(row << 6) + lane] = f2bf_bits(y0) | (f2bf_bits(y1v) << 16); \
        } else { \
            unsigned p1 = yprev[(row << 6) + lane]; \
            unsigned p2 = src[(row << 6) + lane]; \
            int base = (row << 7) + 2 * lane; \
            float2 e = *(const float2*)(ent + base); \
            float2 o2; \
            o2.x = e.x + __uint_as_float(p1 << 16) \
                       + __uint_as_float(p2 << 16) + y0; \
            o2.y = e.y + __uint_as_float(p1 & 0xFFFF0000u) \
                       + __uint_as_float(p2 & 0xFFFF0000u) + y1v; \
            *(float2*)(res + base) = o2; \
        } }

    ROWOUT(0, ax0, ay0, D0);
    ROWOUT(1, ax1, ay1, D1);
    ROWOUT(2, ax2, ay2, D2);
    ROWOUT(3, ax3, ay3, D3);
    ROWOUT(4, ax4, ay4, D4);
    ROWOUT(5, ax5, ay5, D5);
    ROWOUT(6, ax6, ay6, D6);
    ROWOUT(7, ax7, ay7, D7);
#undef ROWOUT
}

extern "C" void kernel_launch(void* const* d_in, const int* in_sizes, int n_in,
                              void* d_out, int out_size, void* d_ws, size_t ws_size,
                              hipStream_t stream) {
    const float* ent  = (const float*)d_in[0];
    const int*   eidx = (const int*)d_in[1];   // [2, E]: head row 0, tail row 1
    const int*   etyp = (const int*)d_in[2];
    const float* wt   = (const float*)d_in[3];
    float*       res  = (float*)d_out;

    const int* head = eidx;
    const int* tail = eidx + N_EDGES;

    // workspace layout (~41 MB). csr is deliberately NOT last: the hop's
    // aligned meta reads may run up to ~2 chunks past a segment; overflow
    // lands in barr (same allocation, always mapped).
    unsigned int* embA = (unsigned int*)d_ws;                 // 12.8 MB
    unsigned int* embB = embA + (size_t)N_ENT * 64;           // 12.8 MB
    int* deg_arr = (int*)(embB + (size_t)N_ENT * 64);         // N_ENT
    int* rg_off  = deg_arr + N_ENT;                           // NRG (pad 6272)
    int* csr  = rg_off + 6272;                                // NB*BCAP 7.2 MB
    int* barr = csr + (size_t)NB * BCAP;                      // N_EDGES 6.4 MB
    int* pack = barr + N_EDGES;                               // 1.25 MB

    gc_part_kernel<<<PART_BLOCKS, 256, 0, stream>>>(head, tail, etyp, barr, pack,
                                                    ent, embA);
    gc_place_kernel<<<NB, 1024, 0, stream>>>(barr, pack, deg_arr, rg_off, csr);

    const int hop_grid = (NRG + 3) / 4;   // 1563 blocks, all co-resident
    // hop1: y1 -> embB
    gc_hop_kernel<<<hop_grid, 256, 0, stream>>>(embA, deg_arr, rg_off, csr, wt,
                                                embB, res, ent, embB, 0);
    // hop2: y2 -> embA
    gc_hop_kernel<<<hop_grid, 256, 0, stream>>>(embB, deg_arr, rg_off, csr, wt,
                                                embA, res, ent, embB, 0);
    // hop3: gathers from embA (y2), reads embB (y1) + ent, writes res only
    gc_hop_kernel<<<hop_grid, 256, 0, stream>>>(embA, deg_arr, rg_off, csr, wt,
                                                embB, res, ent, embB, 1);
}

// Round 5
// 267.238 us; speedup vs baseline: 2.7501x; 2.7501x over previous
//
#include <hip/hip_runtime.h>

#define N_ENT   50000
#define CH      128
#define N_EDGES 1600000
#define N_RELM1 10
#define NB      391           // ceil(N_ENT / 128) buckets of 128 heads
#define BCAP    4608          // real-entry bucket capacity (verified max fits)
#define BCAP_P  8192          // padded csr capacity: 4608 + 512 bins * 7 = 8192 (proven bound)
#define PART_BLOCKS 800
#define CHUNK   (N_EDGES / PART_BLOCKS)   // 2000 exactly
#define NRG     (N_ENT / 8)   // 6250 rowgroups of 8 heads
#define NKEY    512           // (rgl:4)(g2:2)(r:3) sort bins per bucket
#define EPS_N   1e-12f

#define RFL(x) __builtin_amdgcn_readfirstlane(x)

__device__ __forceinline__ unsigned int f2bf_bits(float f) {
    unsigned int x = __float_as_uint(f);
    return (x + 0x7FFFu + ((x >> 16) & 1u)) >> 16;   // RNE; values are finite
}

// Per block: ONE pass over its 2000 edges, stage entry+bucket in LDS,
// histogram, scan, LDS bin-scatter, coalesced write-out. Fused bf16 cvt.
// entry = tail(16) | rel(4)<<16 | hlow(7)<<20
__global__ __launch_bounds__(256) void gc_part_kernel(const int* __restrict__ head,
                                                      const int* __restrict__ tail,
                                                      const int* __restrict__ etyp,
                                                      int* __restrict__ barr,
                                                      int* __restrict__ pack,
                                                      const float* __restrict__ ent,
                                                      unsigned int* __restrict__ emb) {
    __shared__ int hist[512];                // NB bins padded
    __shared__ int boff_s[512];
    __shared__ int fctr[512];
    __shared__ int psum[256];
    __shared__ int stageE[CHUNK];            // raw entries (8 KB)
    __shared__ unsigned short stageB[CHUNK]; // bucket ids (4 KB)
    __shared__ int stage2[CHUNK];            // binned entries (8 KB)
    int tid = threadIdx.x, blk = blockIdx.x;
    for (int i = tid; i < 512; i += 256) { hist[i] = 0; fctr[i] = 0; }
    __syncthreads();
    int lo = blk * CHUNK;
    for (int i = tid; i < CHUNK; i += 256) {
        int e = lo + i;
        int h = head[e];
        int b = h >> 7;
        stageE[i] = (tail[e] & 0xFFFF) | ((etyp[e] - 1) << 16) | ((h & 127) << 20);
        stageB[i] = (unsigned short)b;
        atomicAdd(&hist[b], 1);
    }
    __syncthreads();
    // exclusive scan of 512 bins: 2 bins/thread + 256-ladder
    int a0 = hist[2 * tid], a1 = hist[2 * tid + 1];
    int s2 = a0 + a1;
    psum[tid] = s2;
    __syncthreads();
    for (int d = 1; d < 256; d <<= 1) {
        int t = (tid >= d) ? psum[tid - d] : 0;
        __syncthreads();
        psum[tid] += t;
        __syncthreads();
    }
    int excl = psum[tid] - s2;
    boff_s[2 * tid] = excl;
    boff_s[2 * tid + 1] = excl + a0;
    __syncthreads();
    for (int i = tid; i < CHUNK; i += 256) {
        int b = stageB[i];
        int pos = boff_s[b] + atomicAdd(&fctr[b], 1);
        stage2[pos] = stageE[i];
    }
    __syncthreads();
    for (int i = tid; i < CHUNK; i += 256) barr[lo + i] = stage2[i];
    for (int i = tid; i < NB; i += 256)
        pack[blk * NB + i] = (boff_s[i] << 8) | fctr[i];
    // fused cvt (independent streaming work)
    for (int i = blk * 256 + tid; i < N_ENT * (CH / 2); i += PART_BLOCKS * 256) {
        float2 v = *(const float2*)(ent + 2 * (size_t)i);
        emb[i] = f2bf_bits(v.x) | (f2bf_bits(v.y) << 16);
    }
}

// per bucket: gather the 800 part-block windows to LDS, then sort entries by
// key = (rowgroup:4 | g2:2 | row:3) where g2 = tail>>14 (4 supergroups of
// 16K rows = 3.2 MB gather window, L2-resident chip-wide). Every (g2,row)
// run is PADDED to a multiple of 8 with dummy entries (rel=15 -> zero
// weight), so each 8-edge hop chunk maps to exactly one row. Emits:
//   deg_arr[h]     true in-degree (mean divisor)
//   cpk[grg*8+r]   4 packed bytes: chunk count per g2 for row r
//   rg_off[grg]    csr start (multiple of 8 -> 32B-aligned meta loads)
//   csr            padded entries: tail | rel<<16
__global__ __launch_bounds__(1024) void gc_place_kernel(const int* __restrict__ barr,
                                                        const int* __restrict__ pack,
                                                        int* __restrict__ deg_arr,
                                                        int* __restrict__ rg_off,
                                                        int* __restrict__ cpk,
                                                        int* __restrict__ csr) {
    __shared__ int ent_s[BCAP];
    __shared__ int psum[1024];
    __shared__ int kcnt[NKEY];
    __shared__ int kctr[NKEY];
    __shared__ int kbase[NKEY];
    int b = blockIdx.x, tid = threadIdx.x;
    if (tid < NKEY) { kcnt[tid] = 0; kctr[tid] = 0; }
    int c = 0, o = 0;
    if (tid < PART_BLOCKS) {
        int pk = pack[tid * NB + b];
        c = pk & 255;
        o = pk >> 8;
    }
    psum[tid] = c;
    __syncthreads();
    for (int d = 1; d < 1024; d <<= 1) {
        int t = (tid >= d) ? psum[tid - d] : 0;
        __syncthreads();
        psum[tid] += t;
        __syncthreads();
    }
    int my_off = psum[tid] - c;
    int n = psum[1023];
    const int* src = barr + tid * CHUNK + o;
    for (int k = 0; k < c; ++k) ent_s[my_off + k] = src[k];
    __syncthreads();
    // histogram over 512 keys
    for (int i = tid; i < n; i += 1024) {
        int e = ent_s[i];
        int hl = (e >> 20) & 127;
        int key = ((hl >> 3) << 5) | (((e >> 14) & 3) << 3) | (hl & 7);
        atomicAdd(&kcnt[key], 1);
    }
    __syncthreads();
    // per-row degree + packed per-g2 chunk counts (tid<128: rgl=tid>>3, r=tid&7)
    if (tid < 128) {
        int rgl = tid >> 3, r = tid & 7;
        int base = (rgl << 5) | r;
        int c0 = kcnt[base], c1 = kcnt[base + 8], c2 = kcnt[base + 16], c3 = kcnt[base + 24];
        int h = (b << 7) + tid;
        if (h < N_ENT) {
            deg_arr[h] = c0 + c1 + c2 + c3;
            cpk[(((b << 4) + rgl) << 3) + r] =
                ((c0 + 7) >> 3) | (((c1 + 7) >> 3) << 8) |
                (((c2 + 7) >> 3) << 16) | (((c3 + 7) >> 3) << 24);
        }
    }
    // padded exclusive scan over 512 bins (2 bins/thread on first 256 threads)
    int a0 = 0, a1 = 0, s2 = 0;
    if (tid < 256) {
        a0 = (kcnt[2 * tid] + 7) & ~7;
        a1 = (kcnt[2 * tid + 1] + 7) & ~7;
        s2 = a0 + a1;
        psum[tid] = s2;
    }
    __syncthreads();
    for (int d = 1; d < 256; d <<= 1) {
        int t = (tid < 256 && tid >= d) ? psum[tid - d] : 0;
        __syncthreads();
        if (tid < 256) psum[tid] += t;
        __syncthreads();
    }
    if (tid < 256) {
        int excl = psum[tid] - s2;
        kbase[2 * tid] = excl;
        kbase[2 * tid + 1] = excl + a0;
    }
    __syncthreads();
    int lo = b * BCAP_P;
    if (tid < 16) {
        int grg = (b << 4) + tid;
        if (grg < NRG) rg_off[grg] = lo + kbase[tid << 5];
    }
    // scatter real entries (strip hlow bits; keep tail | rel<<16)
    for (int i = tid; i < n; i += 1024) {
        int e = ent_s[i];
        int hl = (e >> 20) & 127;
        int key = ((hl >> 3) << 5) | (((e >> 14) & 3) << 3) | (hl & 7);
        int pos = lo + kbase[key] + atomicAdd(&kctr[key], 1);
        csr[pos] = e & 0xFFFFF;
    }
    __syncthreads();
    // pad fill: dummy = rel 15 (zero weight row), tail 0
    if (tid < NKEY) {
        int cc = kcnt[tid];
        int pc = (cc + 7) & ~7;
        int p0 = lo + kbase[tid];
        for (int k = cc; k < pc; ++k) csr[p0 + k] = 15 << 16;
    }
}

// one wave64 per 8 rows. ~All waves co-resident (6 blocks/CU * 256 = 1536 of
// 1563); each sweeps g2 = 0..3 in lockstep over its padded runs, so the
// chip-wide gather window is ~3.2 MB (L2-resident). Padded runs make every
// 8-edge chunk single-row -> the accumulator pair is STATIC per run: no
// switch (r2's serializer), no deep pipeline state (r4's spiller). Chunk =
// 2 broadcast int4 meta loads + 8 rfl + 8 gathers + 8 ds_read_b64 + 16 FMA,
// one basic block -> compiler schedules loads ahead of uses freely.
__global__ __launch_bounds__(256, 6) void gc_hop_kernel(
        const unsigned int* __restrict__ src,     // bf16x2 per uint
        const int* __restrict__ deg_arr,
        const int* __restrict__ rg_off,
        const int* __restrict__ cpk,
        const int* __restrict__ csr,
        const float* __restrict__ wt,
        unsigned int* __restrict__ dst,
        float* __restrict__ res,
        const float* __restrict__ ent,
        const unsigned int* __restrict__ yprev,
        int mode) {
    __shared__ float wt_s[16 * CH];   // rows 10..15 ZERO (dummy rel=15 -> 0)
    for (int i = threadIdx.x; i < 16 * CH; i += 256)
        wt_s[i] = (i < N_RELM1 * CH) ? wt[i] : 0.f;
    __syncthreads();

    int wave = threadIdx.x >> 6, lane = threadIdx.x & 63;
    int rg = RFL(blockIdx.x * 4 + wave);
    if (rg >= NRG) return;    // no barriers below

    const int4* dp = (const int4*)deg_arr + rg * 2;
    int4 dd0 = dp[0], dd1 = dp[1];
    const int4* cp = (const int4*)cpk + rg * 2;
    int4 cc0 = cp[0], cc1 = cp[1];
    int segv = rg_off[rg];

    int D0 = RFL(dd0.x), D1 = RFL(dd0.y), D2 = RFL(dd0.z), D3 = RFL(dd0.w);
    int D4 = RFL(dd1.x), D5 = RFL(dd1.y), D6 = RFL(dd1.z), D7 = RFL(dd1.w);
    int C0 = RFL(cc0.x), C1 = RFL(cc0.y), C2 = RFL(cc0.z), C3 = RFL(cc0.w);
    int C4 = RFL(cc1.x), C5 = RFL(cc1.y), C6 = RFL(cc1.z), C7 = RFL(cc1.w);
    int seg = RFL(segv);

    const int4* mp = (const int4*)(csr + seg);   // 32B-aligned (seg % 8 == 0)

    float ax0 = 0.f, ay0 = 0.f, ax1 = 0.f, ay1 = 0.f;
    float ax2 = 0.f, ay2 = 0.f, ax3 = 0.f, ay3 = 0.f;
    float ax4 = 0.f, ay4 = 0.f, ax5 = 0.f, ay5 = 0.f;
    float ax6 = 0.f, ay6 = 0.f, ax7 = 0.f, ay7 = 0.f;

    const unsigned* srcl = src + lane;                  // lane offset folded once
    const float2*   wl   = (const float2*)wt_s + lane;  // wt_s[rel*CH + 2*lane]

#define CHUNK8(axr, ayr) { \
    int4 m0_ = mp[0], m1_ = mp[1]; mp += 2; \
    int p0_ = RFL(m0_.x), p1_ = RFL(m0_.y), p2_ = RFL(m0_.z), p3_ = RFL(m0_.w); \
    int p4_ = RFL(m1_.x), p5_ = RFL(m1_.y), p6_ = RFL(m1_.z), p7_ = RFL(m1_.w); \
    unsigned v0_ = srcl[(unsigned)(p0_ & 0xFFFF) * 64u]; \
    unsigned v1_ = srcl[(unsigned)(p1_ & 0xFFFF) * 64u]; \
    unsigned v2_ = srcl[(unsigned)(p2_ & 0xFFFF) * 64u]; \
    unsigned v3_ = srcl[(unsigned)(p3_ & 0xFFFF) * 64u]; \
    unsigned v4_ = srcl[(unsigned)(p4_ & 0xFFFF) * 64u]; \
    unsigned v5_ = srcl[(unsigned)(p5_ & 0xFFFF) * 64u]; \
    unsigned v6_ = srcl[(unsigned)(p6_ & 0xFFFF) * 64u]; \
    unsigned v7_ = srcl[(unsigned)(p7_ & 0xFFFF) * 64u]; \
    float2 w0_ = wl[((p0_ >> 16) & 15) * 64]; \
    float2 w1_ = wl[((p1_ >> 16) & 15) * 64]; \
    float2 w2_ = wl[((p2_ >> 16) & 15) * 64]; \
    float2 w3_ = wl[((p3_ >> 16) & 15) * 64]; \
    float2 w4_ = wl[((p4_ >> 16) & 15) * 64]; \
    float2 w5_ = wl[((p5_ >> 16) & 15) * 64]; \
    float2 w6_ = wl[((p6_ >> 16) & 15) * 64]; \
    float2 w7_ = wl[((p7_ >> 16) & 15) * 64]; \
    axr = fmaf(__uint_as_float(v0_ << 16), w0_.x, axr); \
    ayr = fmaf(__uint_as_float(v0_ & 0xFFFF0000u), w0_.y, ayr); \
    axr = fmaf(__uint_as_float(v1_ << 16), w1_.x, axr); \
    ayr = fmaf(__uint_as_float(v1_ & 0xFFFF0000u), w1_.y, ayr); \
    axr = fmaf(__uint_as_float(v2_ << 16), w2_.x, axr); \
    ayr = fmaf(__uint_as_float(v2_ & 0xFFFF0000u), w2_.y, ayr); \
    axr = fmaf(__uint_as_float(v3_ << 16), w3_.x, axr); \
    ayr = fmaf(__uint_as_float(v3_ & 0xFFFF0000u), w3_.y, ayr); \
    axr = fmaf(__uint_as_float(v4_ << 16), w4_.x, axr); \
    ayr = fmaf(__uint_as_float(v4_ & 0xFFFF0000u), w4_.y, ayr); \
    axr = fmaf(__uint_as_float(v5_ << 16), w5_.x, axr); \
    ayr = fmaf(__uint_as_float(v5_ & 0xFFFF0000u), w5_.y, ayr); \
    axr = fmaf(__uint_as_float(v6_ << 16), w6_.x, axr); \
    ayr = fmaf(__uint_as_float(v6_ & 0xFFFF0000u), w6_.y, ayr); \
    axr = fmaf(__uint_as_float(v7_ << 16), w7_.x, axr); \
    ayr = fmaf(__uint_as_float(v7_ & 0xFFFF0000u), w7_.y, ayr); \
}

#define RUN(axr, ayr, Cr) { \
    int n_ = (Cr >> sh) & 255; \
    for (int c_ = 0; c_ < n_; ++c_) CHUNK8(axr, ayr) \
}

    for (int g2 = 0; g2 < 4; ++g2) {
        int sh = g2 << 3;
        RUN(ax0, ay0, C0)
        RUN(ax1, ay1, C1)
        RUN(ax2, ay2, C2)
        RUN(ax3, ay3, C3)
        RUN(ax4, ay4, C4)
        RUN(ax5, ay5, C5)
        RUN(ax6, ay6, C6)
        RUN(ax7, ay7, C7)
    }
#undef RUN
#undef CHUNK8

#define ROWOUT(r, axr, ayr, Dr) { \
        int row = (rg << 3) + r; \
        float invd = 1.0f / fmaxf((float)Dr, 1.0f); \
        float x0 = axr * invd, x1 = ayr * invd; \
        float s = x0 * x0 + x1 * x1; \
        _Pragma("unroll") \
        for (int o = 32; o; o >>= 1) s += __shfl_xor(s, o, 64); \
        float inv = 1.0f / fmaxf(sqrtf(s), EPS_N); \
        float y0 = x0 * inv, y1v = x1 * inv; \
        if (mode == 0) { \
            dst[(row << 6) + lane] = f2bf_bits(y0) | (f2bf_bits(y1v) << 16); \
        } else { \
            unsigned p1 = yprev[(row << 6) + lane]; \
            unsigned p2 = src[(row << 6) + lane]; \
            int base = (row << 7) + 2 * lane; \
            float2 e = *(const float2*)(ent + base); \
            float2 o2; \
            o2.x = e.x + __uint_as_float(p1 << 16) \
                       + __uint_as_float(p2 << 16) + y0; \
            o2.y = e.y + __uint_as_float(p1 & 0xFFFF0000u) \
                       + __uint_as_float(p2 & 0xFFFF0000u) + y1v; \
            *(float2*)(res + base) = o2; \
        } }

    ROWOUT(0, ax0, ay0, D0);
    ROWOUT(1, ax1, ay1, D1);
    ROWOUT(2, ax2, ay2, D2);
    ROWOUT(3, ax3, ay3, D3);
    ROWOUT(4, ax4, ay4, D4);
    ROWOUT(5, ax5, ay5, D5);
    ROWOUT(6, ax6, ay6, D6);
    ROWOUT(7, ax7, ay7, D7);
#undef ROWOUT
}

extern "C" void kernel_launch(void* const* d_in, const int* in_sizes, int n_in,
                              void* d_out, int out_size, void* d_ws, size_t ws_size,
                              hipStream_t stream) {
    const float* ent  = (const float*)d_in[0];
    const int*   eidx = (const int*)d_in[1];   // [2, E]: head row 0, tail row 1
    const int*   etyp = (const int*)d_in[2];
    const float* wt   = (const float*)d_in[3];
    float*       res  = (float*)d_out;

    const int* head = eidx;
    const int* tail = eidx + N_EDGES;

    // workspace layout (38.8 MB total). barr+pack ALIAS embB: they are dead
    // after gc_place_kernel completes, and embB is first written by hop1
    // (stream-ordered after place). csr is exact-sized: padded runs mean the
    // hop's meta reads never cross a run end (no OOB, no guard region).
    unsigned int* embA = (unsigned int*)d_ws;                 // 12.8 MB
    unsigned int* embB = embA + (size_t)N_ENT * 64;           // 12.8 MB
    int* barr = (int*)embB;                                   // alias (6.4 MB)
    int* pack = (int*)embB + N_EDGES;                         // alias (1.25 MB)
    int* deg_arr = (int*)(embB + (size_t)N_ENT * 64);         // 0.2 MB
    int* rg_off  = deg_arr + N_ENT;                           // pad 6272
    int* cpk     = rg_off + 6272;                             // 0.2 MB
    int* csr     = cpk + (size_t)NRG * 8;                     // 12.8 MB (NB*BCAP_P)

    gc_part_kernel<<<PART_BLOCKS, 256, 0, stream>>>(head, tail, etyp, barr, pack,
                                                    ent, embA);
    gc_place_kernel<<<NB, 1024, 0, stream>>>(barr, pack, deg_arr, rg_off, cpk, csr);

    const int hop_grid = (NRG + 3) / 4;   // 1563 blocks (1536 co-resident)
    // hop1: y1 -> embB
    gc_hop_kernel<<<hop_grid, 256, 0, stream>>>(embA, deg_arr, rg_off, cpk, csr,
                                                wt, embB, res, ent, embB, 0);
    // hop2: y2 -> embA
    gc_hop_kernel<<<hop_grid, 256, 0, stream>>>(embB, deg_arr, rg_off, cpk, csr,
                                                wt, embA, res, ent, embB, 0);
    // hop3: gathers from embA (y2), reads embB (y1) + ent, writes res only
    gc_hop_kernel<<<hop_grid, 256, 0, stream>>>(embA, deg_arr, rg_off, cpk, csr,
                                                wt, embB, res, ent, embB, 1);
}

// Round 6
// 265.320 us; speedup vs baseline: 2.7699x; 1.0072x over previous
//
#include <hip/hip_runtime.h>

#define N_ENT   50000
#define CH      128
#define N_EDGES 1600000
#define N_RELM1 10
#define NB      391           // ceil(N_ENT / 128) buckets of 128 heads
#define BCAP    4608          // real-entry bucket capacity (verified max fits)
#define BCAP_P  8192          // padded csr capacity: 4608 + 512 bins * 7 = 8192 (proven bound)
#define PART_BLOCKS 800
#define CHUNK   (N_EDGES / PART_BLOCKS)   // 2000 exactly
#define NRG     (N_ENT / 4)   // 12500 rowgroups of 4 heads (TLP: 32 waves/CU)
#define NKEY    512           // (rgl:5)(g2:2)(r:2) sort bins per bucket
#define EPS_N   1e-12f

#define RFL(x) __builtin_amdgcn_readfirstlane(x)

__device__ __forceinline__ unsigned int f2bf_bits(float f) {
    unsigned int x = __float_as_uint(f);
    return (x + 0x7FFFu + ((x >> 16) & 1u)) >> 16;   // RNE; values are finite
}

// Per block: ONE pass over its 2000 edges, stage entry+bucket in LDS,
// histogram, scan, LDS bin-scatter, coalesced write-out. Fused bf16 cvt.
// entry = tail(16) | rel(4)<<16 | hlow(7)<<20
__global__ __launch_bounds__(256) void gc_part_kernel(const int* __restrict__ head,
                                                      const int* __restrict__ tail,
                                                      const int* __restrict__ etyp,
                                                      int* __restrict__ barr,
                                                      int* __restrict__ pack,
                                                      const float* __restrict__ ent,
                                                      unsigned int* __restrict__ emb) {
    __shared__ int hist[512];                // NB bins padded
    __shared__ int boff_s[512];
    __shared__ int fctr[512];
    __shared__ int psum[256];
    __shared__ int stageE[CHUNK];            // raw entries (8 KB)
    __shared__ unsigned short stageB[CHUNK]; // bucket ids (4 KB)
    __shared__ int stage2[CHUNK];            // binned entries (8 KB)
    int tid = threadIdx.x, blk = blockIdx.x;
    for (int i = tid; i < 512; i += 256) { hist[i] = 0; fctr[i] = 0; }
    __syncthreads();
    int lo = blk * CHUNK;
    for (int i = tid; i < CHUNK; i += 256) {
        int e = lo + i;
        int h = head[e];
        int b = h >> 7;
        stageE[i] = (tail[e] & 0xFFFF) | ((etyp[e] - 1) << 16) | ((h & 127) << 20);
        stageB[i] = (unsigned short)b;
        atomicAdd(&hist[b], 1);
    }
    __syncthreads();
    // exclusive scan of 512 bins: 2 bins/thread + 256-ladder
    int a0 = hist[2 * tid], a1 = hist[2 * tid + 1];
    int s2 = a0 + a1;
    psum[tid] = s2;
    __syncthreads();
    for (int d = 1; d < 256; d <<= 1) {
        int t = (tid >= d) ? psum[tid - d] : 0;
        __syncthreads();
        psum[tid] += t;
        __syncthreads();
    }
    int excl = psum[tid] - s2;
    boff_s[2 * tid] = excl;
    boff_s[2 * tid + 1] = excl + a0;
    __syncthreads();
    for (int i = tid; i < CHUNK; i += 256) {
        int b = stageB[i];
        int pos = boff_s[b] + atomicAdd(&fctr[b], 1);
        stage2[pos] = stageE[i];
    }
    __syncthreads();
    for (int i = tid; i < CHUNK; i += 256) barr[lo + i] = stage2[i];
    for (int i = tid; i < NB; i += 256)
        pack[blk * NB + i] = (boff_s[i] << 8) | fctr[i];
    // fused cvt (independent streaming work)
    for (int i = blk * 256 + tid; i < N_ENT * (CH / 2); i += PART_BLOCKS * 256) {
        float2 v = *(const float2*)(ent + 2 * (size_t)i);
        emb[i] = f2bf_bits(v.x) | (f2bf_bits(v.y) << 16);
    }
}

// per bucket: gather the 800 part-block windows to LDS, then sort entries by
// key = (rowgroup:5 | g2:2 | row:2) where g2 = tail>>14 (4 supergroups of
// 16K rows = 3.2 MB gather window, L2-resident chip-wide). Every (g2,row)
// run is PADDED to a multiple of 8 with dummy entries (rel=15 -> zero
// weight), so each 8-edge hop chunk maps to exactly one row. Emits:
//   deg_arr[h]       true in-degree (mean divisor)
//   cpk[grg*4+r]     4 packed bytes: chunk count per g2 for row r
//   rg_off[grg]      csr start (multiple of 8 -> 32B-aligned meta loads)
//   csr              padded entries: tail | rel<<16
__global__ __launch_bounds__(1024) void gc_place_kernel(const int* __restrict__ barr,
                                                        const int* __restrict__ pack,
                                                        int* __restrict__ deg_arr,
                                                        int* __restrict__ rg_off,
                                                        int* __restrict__ cpk,
                                                        int* __restrict__ csr) {
    __shared__ int ent_s[BCAP];
    __shared__ int psum[1024];
    __shared__ int kcnt[NKEY];
    __shared__ int kctr[NKEY];
    __shared__ int kbase[NKEY];
    int b = blockIdx.x, tid = threadIdx.x;
    if (tid < NKEY) { kcnt[tid] = 0; kctr[tid] = 0; }
    int c = 0, o = 0;
    if (tid < PART_BLOCKS) {
        int pk = pack[tid * NB + b];
        c = pk & 255;
        o = pk >> 8;
    }
    psum[tid] = c;
    __syncthreads();
    for (int d = 1; d < 1024; d <<= 1) {
        int t = (tid >= d) ? psum[tid - d] : 0;
        __syncthreads();
        psum[tid] += t;
        __syncthreads();
    }
    int my_off = psum[tid] - c;
    int n = psum[1023];
    const int* src = barr + tid * CHUNK + o;
    for (int k = 0; k < c; ++k) ent_s[my_off + k] = src[k];
    __syncthreads();
    // histogram over 512 keys
    for (int i = tid; i < n; i += 1024) {
        int e = ent_s[i];
        int hl = (e >> 20) & 127;
        int key = ((hl >> 2) << 4) | (((e >> 14) & 3) << 2) | (hl & 3);
        atomicAdd(&kcnt[key], 1);
    }
    __syncthreads();
    // per-row degree + packed per-g2 chunk counts (tid<128: rgl=tid>>2, r=tid&3)
    if (tid < 128) {
        int rgl = tid >> 2, r = tid & 3;
        int base = (rgl << 4) | r;
        int c0 = kcnt[base], c1 = kcnt[base + 4], c2 = kcnt[base + 8], c3 = kcnt[base + 12];
        int h = (b << 7) + tid;
        if (h < N_ENT) {
            deg_arr[h] = c0 + c1 + c2 + c3;
            cpk[(((b << 5) + rgl) << 2) + r] =
                ((c0 + 7) >> 3) | (((c1 + 7) >> 3) << 8) |
                (((c2 + 7) >> 3) << 16) | (((c3 + 7) >> 3) << 24);
        }
    }
    // padded exclusive scan over 512 bins (2 bins/thread on first 256 threads)
    int a0 = 0, a1 = 0, s2 = 0;
    if (tid < 256) {
        a0 = (kcnt[2 * tid] + 7) & ~7;
        a1 = (kcnt[2 * tid + 1] + 7) & ~7;
        s2 = a0 + a1;
        psum[tid] = s2;
    }
    __syncthreads();
    for (int d = 1; d < 256; d <<= 1) {
        int t = (tid < 256 && tid >= d) ? psum[tid - d] : 0;
        __syncthreads();
        if (tid < 256) psum[tid] += t;
        __syncthreads();
    }
    if (tid < 256) {
        int excl = psum[tid] - s2;
        kbase[2 * tid] = excl;
        kbase[2 * tid + 1] = excl + a0;
    }
    __syncthreads();
    int lo = b * BCAP_P;
    if (tid < 32) {
        int grg = (b << 5) + tid;
        if (grg < NRG) rg_off[grg] = lo + kbase[tid << 4];
    }
    // scatter real entries (strip hlow bits; keep tail | rel<<16)
    for (int i = tid; i < n; i += 1024) {
        int e = ent_s[i];
        int hl = (e >> 20) & 127;
        int key = ((hl >> 2) << 4) | (((e >> 14) & 3) << 2) | (hl & 3);
        int pos = lo + kbase[key] + atomicAdd(&kctr[key], 1);
        csr[pos] = e & 0xFFFFF;
    }
    __syncthreads();
    // pad fill: dummy = rel 15 (zero weight row), tail 0
    if (tid < NKEY) {
        int cc = kcnt[tid];
        int pc = (cc + 7) & ~7;
        int p0 = lo + kbase[tid];
        for (int k = cc; k < pc; ++k) csr[p0 + k] = 15 << 16;
    }
}

// one wave64 per 4 rows -> 12500 waves = 3125 blocks: up to 8 blocks/CU =
// 32 waves/CU (HW cap), 2x the latency hiding of the 8-row variant (r5 was
// grid-capped at ~24 waves/CU, latency-bound: VALUBusy 42%, occ 45%).
// Waves sweep g2 = 0..3 over padded runs -> chip-wide gather window stays
// roughly L2-sized. Padded runs keep every 8-edge chunk single-row: static
// accumulator pair per run, no switch, no deep pipeline state.
__global__ __launch_bounds__(256, 8) void gc_hop_kernel(
        const unsigned int* __restrict__ src,     // bf16x2 per uint
        const int* __restrict__ deg_arr,
        const int* __restrict__ rg_off,
        const int* __restrict__ cpk,
        const int* __restrict__ csr,
        const float* __restrict__ wt,
        unsigned int* __restrict__ dst,
        float* __restrict__ res,
        const float* __restrict__ ent,
        const unsigned int* __restrict__ yprev,
        int mode) {
    __shared__ float wt_s[16 * CH];   // rows 10..15 ZERO (dummy rel=15 -> 0)
    for (int i = threadIdx.x; i < 16 * CH; i += 256)
        wt_s[i] = (i < N_RELM1 * CH) ? wt[i] : 0.f;
    __syncthreads();

    int wave = threadIdx.x >> 6, lane = threadIdx.x & 63;
    int rg = RFL(blockIdx.x * 4 + wave);
    if (rg >= NRG) return;    // no barriers below

    int4 dd = ((const int4*)deg_arr)[rg];
    int4 cc = ((const int4*)cpk)[rg];
    int segv = rg_off[rg];

    int D0 = RFL(dd.x), D1 = RFL(dd.y), D2 = RFL(dd.z), D3 = RFL(dd.w);
    int C0 = RFL(cc.x), C1 = RFL(cc.y), C2 = RFL(cc.z), C3 = RFL(cc.w);
    int seg = RFL(segv);

    const int4* mp = (const int4*)(csr + seg);   // 32B-aligned (seg % 8 == 0)

    float ax0 = 0.f, ay0 = 0.f, ax1 = 0.f, ay1 = 0.f;
    float ax2 = 0.f, ay2 = 0.f, ax3 = 0.f, ay3 = 0.f;

    const unsigned* srcl = src + lane;                  // lane offset folded once
    const float2*   wl   = (const float2*)wt_s + lane;  // wt_s[rel*CH + 2*lane]

#define CHUNK8(axr, ayr) { \
    int4 m0_ = mp[0], m1_ = mp[1]; mp += 2; \
    int p0_ = RFL(m0_.x), p1_ = RFL(m0_.y), p2_ = RFL(m0_.z), p3_ = RFL(m0_.w); \
    int p4_ = RFL(m1_.x), p5_ = RFL(m1_.y), p6_ = RFL(m1_.z), p7_ = RFL(m1_.w); \
    unsigned v0_ = srcl[(unsigned)(p0_ & 0xFFFF) * 64u]; \
    unsigned v1_ = srcl[(unsigned)(p1_ & 0xFFFF) * 64u]; \
    unsigned v2_ = srcl[(unsigned)(p2_ & 0xFFFF) * 64u]; \
    unsigned v3_ = srcl[(unsigned)(p3_ & 0xFFFF) * 64u]; \
    unsigned v4_ = srcl[(unsigned)(p4_ & 0xFFFF) * 64u]; \
    unsigned v5_ = srcl[(unsigned)(p5_ & 0xFFFF) * 64u]; \
    unsigned v6_ = srcl[(unsigned)(p6_ & 0xFFFF) * 64u]; \
    unsigned v7_ = srcl[(unsigned)(p7_ & 0xFFFF) * 64u]; \
    float2 w0_ = wl[((p0_ >> 16) & 15) * 64]; \
    float2 w1_ = wl[((p1_ >> 16) & 15) * 64]; \
    float2 w2_ = wl[((p2_ >> 16) & 15) * 64]; \
    float2 w3_ = wl[((p3_ >> 16) & 15) * 64]; \
    float2 w4_ = wl[((p4_ >> 16) & 15) * 64]; \
    float2 w5_ = wl[((p5_ >> 16) & 15) * 64]; \
    float2 w6_ = wl[((p6_ >> 16) & 15) * 64]; \
    float2 w7_ = wl[((p7_ >> 16) & 15) * 64]; \
    axr = fmaf(__uint_as_float(v0_ << 16), w0_.x, axr); \
    ayr = fmaf(__uint_as_float(v0_ & 0xFFFF0000u), w0_.y, ayr); \
    axr = fmaf(__uint_as_float(v1_ << 16), w1_.x, axr); \
    ayr = fmaf(__uint_as_float(v1_ & 0xFFFF0000u), w1_.y, ayr); \
    axr = fmaf(__uint_as_float(v2_ << 16), w2_.x, axr); \
    ayr = fmaf(__uint_as_float(v2_ & 0xFFFF0000u), w2_.y, ayr); \
    axr = fmaf(__uint_as_float(v3_ << 16), w3_.x, axr); \
    ayr = fmaf(__uint_as_float(v3_ & 0xFFFF0000u), w3_.y, ayr); \
    axr = fmaf(__uint_as_float(v4_ << 16), w4_.x, axr); \
    ayr = fmaf(__uint_as_float(v4_ & 0xFFFF0000u), w4_.y, ayr); \
    axr = fmaf(__uint_as_float(v5_ << 16), w5_.x, axr); \
    ayr = fmaf(__uint_as_float(v5_ & 0xFFFF0000u), w5_.y, ayr); \
    axr = fmaf(__uint_as_float(v6_ << 16), w6_.x, axr); \
    ayr = fmaf(__uint_as_float(v6_ & 0xFFFF0000u), w6_.y, ayr); \
    axr = fmaf(__uint_as_float(v7_ << 16), w7_.x, axr); \
    ayr = fmaf(__uint_as_float(v7_ & 0xFFFF0000u), w7_.y, ayr); \
}

#define RUN(axr, ayr, Cr) { \
    int n_ = (Cr >> sh) & 255; \
    for (int c_ = 0; c_ < n_; ++c_) CHUNK8(axr, ayr) \
}

    for (int g2 = 0; g2 < 4; ++g2) {
        int sh = g2 << 3;
        RUN(ax0, ay0, C0)
        RUN(ax1, ay1, C1)
        RUN(ax2, ay2, C2)
        RUN(ax3, ay3, C3)
    }
#undef RUN
#undef CHUNK8

#define ROWOUT(r, axr, ayr, Dr) { \
        int row = (rg << 2) + r; \
        float invd = 1.0f / fmaxf((float)Dr, 1.0f); \
        float x0 = axr * invd, x1 = ayr * invd; \
        float s = x0 * x0 + x1 * x1; \
        _Pragma("unroll") \
        for (int o = 32; o; o >>= 1) s += __shfl_xor(s, o, 64); \
        float inv = 1.0f / fmaxf(sqrtf(s), EPS_N); \
        float y0 = x0 * inv, y1v = x1 * inv; \
        if (mode == 0) { \
            dst[(row << 6) + lane] = f2bf_bits(y0) | (f2bf_bits(y1v) << 16); \
        } else { \
            unsigned p1 = yprev[(row << 6) + lane]; \
            unsigned p2 = src[(row << 6) + lane]; \
            int base = (row << 7) + 2 * lane; \
            float2 e = *(const float2*)(ent + base); \
            float2 o2; \
            o2.x = e.x + __uint_as_float(p1 << 16) \
                       + __uint_as_float(p2 << 16) + y0; \
            o2.y = e.y + __uint_as_float(p1 & 0xFFFF0000u) \
                       + __uint_as_float(p2 & 0xFFFF0000u) + y1v; \
            *(float2*)(res + base) = o2; \
        } }

    ROWOUT(0, ax0, ay0, D0);
    ROWOUT(1, ax1, ay1, D1);
    ROWOUT(2, ax2, ay2, D2);
    ROWOUT(3, ax3, ay3, D3);
#undef ROWOUT
}

extern "C" void kernel_launch(void* const* d_in, const int* in_sizes, int n_in,
                              void* d_out, int out_size, void* d_ws, size_t ws_size,
                              hipStream_t stream) {
    const float* ent  = (const float*)d_in[0];
    const int*   eidx = (const int*)d_in[1];   // [2, E]: head row 0, tail row 1
    const int*   etyp = (const int*)d_in[2];
    const float* wt   = (const float*)d_in[3];
    float*       res  = (float*)d_out;

    const int* head = eidx;
    const int* tail = eidx + N_EDGES;

    // workspace layout (~38.9 MB). barr+pack ALIAS embB (dead until hop1).
    // csr exact-sized: padded runs mean meta reads never cross a run end.
    unsigned int* embA = (unsigned int*)d_ws;                 // 12.8 MB
    unsigned int* embB = embA + (size_t)N_ENT * 64;           // 12.8 MB
    int* barr = (int*)embB;                                   // alias (6.4 MB)
    int* pack = (int*)embB + N_EDGES;                         // alias (1.25 MB)
    int* deg_arr = (int*)(embB + (size_t)N_ENT * 64);         // 0.2 MB
    int* rg_off  = deg_arr + N_ENT;                           // NRG (pad 12544)
    int* cpk     = rg_off + 12544;                            // 0.2 MB
    int* csr     = cpk + (size_t)NRG * 4;                     // 12.8 MB (NB*BCAP_P)

    gc_part_kernel<<<PART_BLOCKS, 256, 0, stream>>>(head, tail, etyp, barr, pack,
                                                    ent, embA);
    gc_place_kernel<<<NB, 1024, 0, stream>>>(barr, pack, deg_arr, rg_off, cpk, csr);

    const int hop_grid = NRG / 4;   // 3125 blocks of 4 waves = 12500 waves
    // hop1: y1 -> embB
    gc_hop_kernel<<<hop_grid, 256, 0, stream>>>(embA, deg_arr, rg_off, cpk, csr,
                                                wt, embB, res, ent, embB, 0);
    // hop2: y2 -> embA
    gc_hop_kernel<<<hop_grid, 256, 0, stream>>>(embB, deg_arr, rg_off, cpk, csr,
                                                wt, embA, res, ent, embB, 0);
    // hop3: gathers from embA (y2), reads embB (y1) + ent, writes res only
    gc_hop_kernel<<<hop_grid, 256, 0, stream>>>(embA, deg_arr, rg_off, cpk, csr,
                                                wt, embB, res, ent, embB, 1);
}